// Round 12
// baseline (24940.994 us; speedup 1.0000x reference)
//
#include <hip/hip_runtime.h>

typedef __attribute__((ext_vector_type(8))) short bf8;
typedef __attribute__((ext_vector_type(8))) unsigned short us8;
typedef __attribute__((ext_vector_type(4))) unsigned short us4;
typedef __attribute__((ext_vector_type(4))) float f4;

#define NB 256
#define OUT_HX_OFF ((size_t)256 * 256 * 1024)
#define OUT_CX_OFF (OUT_HX_OFF + (size_t)256 * 1024)

static __device__ __forceinline__ unsigned short f2bf(float f) {
    unsigned u = __builtin_bit_cast(unsigned, f);
    return (unsigned short)((u + 0x7FFFu + ((u >> 16) & 1u)) >> 16);
}
static __device__ __forceinline__ float bf2f(unsigned short h) {
    return __builtin_bit_cast(float, (unsigned)h << 16);
}
static __device__ __forceinline__ float sigm(float x) {
    return 1.0f / (1.0f + __expf(-x));
}

#define MFMA16(a, b, c) __builtin_amdgcn_mfma_f32_16x16x32_bf16(a, b, c, 0, 0, 0)

#define GLDS16(g, l)                                                        \
    __builtin_amdgcn_global_load_lds(                                       \
        (const __attribute__((address_space(1))) void*)(g),                 \
        (__attribute__((address_space(3))) void*)(l), 16, 0, 0)

#define WAITV(n) asm volatile("s_waitcnt vmcnt(" #n ")" ::: "memory")
#define WAITL0 asm volatile("s_waitcnt lgkmcnt(0)" ::: "memory")
#define BARRIER                                                             \
    do {                                                                    \
        __builtin_amdgcn_s_barrier();                                       \
        __builtin_amdgcn_sched_barrier(0);                                  \
    } while (0)

template <int R>
static __device__ __forceinline__ void stage64(const unsigned short* g, int gstride,
                                               unsigned short* lds, int wave, int lane) {
#pragma unroll
    for (int j = 0; j < R / 32; ++j) {
        const int seg = wave * (R / 32) + j;
        const int row = seg * 8 + (lane >> 3);
        const int chunk = (lane & 7) ^ (row & 7);
        GLDS16(g + (size_t)row * gstride + chunk * 8, lds + seg * 512);
    }
}

static __device__ __forceinline__ bf8 fragld(const unsigned short* lds, int row, int ck) {
    return *(const bf8*)&lds[row * 64 + (((ck) ^ (row & 7)) << 3)];
}

// ---------------- one-time: f32 -> bf16 convert ----------------
__global__ __launch_bounds__(256) void k_x2bf(const float* __restrict__ src,
                                              unsigned short* __restrict__ dst, int n4) {
    const int stride = gridDim.x * 256;
    for (int i = blockIdx.x * 256 + threadIdx.x; i < n4; i += stride) {
        f4 v = ((const f4*)src)[i];
        us4 o;
        o[0] = f2bf(v[0]); o[1] = f2bf(v[1]); o[2] = f2bf(v[2]); o[3] = f2bf(v[3]);
        ((us4*)dst)[i] = o;
    }
}

// ---------------- one-time: weight transpose f32[K][N] -> bf16[N][K] ----------------
__global__ __launch_bounds__(256) void k_transpose(const float* __restrict__ src,
                                                   unsigned short* __restrict__ dst,
                                                   int K, int N) {
    __shared__ float tile[32][33];
    const int tx = threadIdx.x & 31, ty = threadIdx.x >> 5;
    const int n0 = blockIdx.x * 32, k0 = blockIdx.y * 32;
#pragma unroll
    for (int i = 0; i < 4; ++i) tile[ty + i * 8][tx] = src[(size_t)(k0 + ty + i * 8) * N + n0 + tx];
    __syncthreads();
#pragma unroll
    for (int i = 0; i < 4; ++i)
        dst[(size_t)(n0 + ty + i * 8) * K + k0 + tx] = f2bf(tile[tx][ty + i * 8]);
}

// ---------------- one-time: fused weights, all 18 products in one launch ----------------
__global__ __launch_bounds__(256) void k_wfz(const unsigned short* __restrict__ wqkvT,
                                             const unsigned short* __restrict__ wgnt,
                                             unsigned short* __restrict__ wbigX,
                                             unsigned short* __restrict__ wbigH) {
    __shared__ unsigned short sA[2][128 * 64];
    __shared__ unsigned short sB[2][128 * 64];
    const int tid = threadIdx.x, lane = tid & 63, wave = tid >> 6;
    const int z = blockIdx.z, j = z >> 1, xh = z & 1;
    const int gp = j / 3, which = j % 3;
    const int selg = (gp == 2) ? 3 : gp;
    const unsigned short* Aab = wqkvT + ((size_t)gp * 3072 + which * 1024) * 1024;
    const unsigned short* Bb = wgnt + (size_t)selg * 2048 * 1024 + (size_t)xh * 1024 * 1024;
    unsigned short* outp = (xh ? wbigH : wbigX) + (size_t)j * 1024 * 1024;
    const int n0 = blockIdx.x * 128, m0 = blockIdx.y * 128;
    const int wy = (wave >> 1) * 64, wx = (wave & 1) * 64;
    const int fr = lane & 15, fq = lane >> 4;
    f4 acc[4][4] = {};

    stage64<128>(Aab + (size_t)m0 * 1024, 1024, sA[0], wave, lane);
    stage64<128>(Bb + (size_t)n0 * 1024, 1024, sB[0], wave, lane);
    WAITV(0); BARRIER;
#pragma unroll
    for (int i = 0; i < 16; ++i) {
        if (i + 1 < 16) {
            stage64<128>(Aab + (size_t)m0 * 1024 + (i + 1) * 64, 1024, sA[(i + 1) & 1], wave, lane);
            stage64<128>(Bb + (size_t)n0 * 1024 + (i + 1) * 64, 1024, sB[(i + 1) & 1], wave, lane);
        }
        const unsigned short* A = sA[i & 1];
        const unsigned short* Bm = sB[i & 1];
#pragma unroll
        for (int ks = 0; ks < 2; ++ks) {
            bf8 af[4], bfv[4];
#pragma unroll
            for (int mi = 0; mi < 4; ++mi) af[mi] = fragld(A, wy + mi * 16 + fr, ks * 4 + fq);
#pragma unroll
            for (int ni = 0; ni < 4; ++ni) bfv[ni] = fragld(Bm, wx + ni * 16 + fr, ks * 4 + fq);
#pragma unroll
            for (int mi = 0; mi < 4; ++mi)
#pragma unroll
                for (int ni = 0; ni < 4; ++ni)
                    acc[mi][ni] = MFMA16(af[mi], bfv[ni], acc[mi][ni]);
        }
        if (i + 1 < 16) { WAITL0; WAITV(0); BARRIER; }
    }
#pragma unroll
    for (int mi = 0; mi < 4; ++mi)
#pragma unroll
        for (int ni = 0; ni < 4; ++ni) {
            const int col = n0 + wx + ni * 16 + fr;
#pragma unroll
            for (int j2 = 0; j2 < 4; ++j2) {
                const int row = m0 + wy + mi * 16 + fq * 4 + j2;
                outp[(size_t)row * 1024 + col] = f2bf(acc[mi][ni][j2]);
            }
        }
}

// ---------------- one-time: wbig segment 9 (gate-2 rows) from wgT ----------------
__global__ __launch_bounds__(256) void k_seg9(const unsigned short* __restrict__ wgT,
                                              unsigned short* __restrict__ wbigX,
                                              unsigned short* __restrict__ wbigH) {
    const int d = blockIdx.x, k4 = threadIdx.x * 4;
    us4 vx = *(const us4*)(wgT + (size_t)(2048 + d) * 2048 + k4);
    us4 vh = *(const us4*)(wgT + (size_t)(2048 + d) * 2048 + 1024 + k4);
    *(us4*)(wbigX + (size_t)(9216 + d) * 1024 + k4) = vx;
    *(us4*)(wbigH + (size_t)(9216 + d) * 1024 + k4) = vh;
}

// ---------------- one-time: cbig[n] = bg[g']@Wqkv + bqkv  (f32) ----------------
__global__ __launch_bounds__(256) void k_cbig(const float* __restrict__ bg,
                                              const float* __restrict__ Wq,
                                              const float* __restrict__ Wk,
                                              const float* __restrict__ Wv,
                                              const float* __restrict__ bq,
                                              const float* __restrict__ bk,
                                              const float* __restrict__ bv,
                                              float* __restrict__ cbig) {
    const int n = blockIdx.x * 256 + threadIdx.x;
    const int j = n >> 10, d = n & 1023;
    float s;
    if (j < 9) {
        const int gp = j / 3, which = j % 3;
        const int selg = (gp == 2) ? 3 : gp;
        const float* W = which == 0 ? Wq : (which == 1 ? Wk : Wv);
        const float* bqkv = which == 0 ? bq : (which == 1 ? bk : bv);
        s = bqkv[gp * 1024 + d];
        const float* wb = W + (size_t)gp * 1024 * 1024;
        const float* bgb = bg + selg * 1024;
        for (int k = 0; k < 1024; ++k) s += bgb[k] * wb[(size_t)k * 1024 + d];
    } else {
        s = bg[2048 + d];
    }
    cbig[n] = s;
}

// ---------------- chunked: XBIG = xbf_chunk @ wbigX^T + cbig ----------------
__global__ __launch_bounds__(256) void k_xbig(const unsigned short* __restrict__ xbf,
                                              const unsigned short* __restrict__ wbigX,
                                              const float* __restrict__ cbig,
                                              unsigned short* __restrict__ XBIG) {
    __shared__ unsigned short sA[2][128 * 64];
    __shared__ unsigned short sB[2][128 * 64];
    const int tid = threadIdx.x, lane = tid & 63, wave = tid >> 6;
    const int n0 = blockIdx.x * 128;
    const size_t m0 = (size_t)blockIdx.y * 128;
    const int wy = (wave >> 1) * 64, wx = (wave & 1) * 64;
    const int fr = lane & 15, fq = lane >> 4;
    f4 acc[4][4] = {};

    stage64<128>(xbf + m0 * 1024, 1024, sA[0], wave, lane);
    stage64<128>(wbigX + (size_t)n0 * 1024, 1024, sB[0], wave, lane);
    WAITV(0); BARRIER;
#pragma unroll
    for (int i = 0; i < 16; ++i) {
        if (i + 1 < 16) {
            stage64<128>(xbf + m0 * 1024 + (i + 1) * 64, 1024, sA[(i + 1) & 1], wave, lane);
            stage64<128>(wbigX + (size_t)n0 * 1024 + (i + 1) * 64, 1024, sB[(i + 1) & 1], wave, lane);
        }
        const unsigned short* A = sA[i & 1];
        const unsigned short* Bm = sB[i & 1];
#pragma unroll
        for (int ks = 0; ks < 2; ++ks) {
            bf8 af[4], bfv[4];
#pragma unroll
            for (int mi = 0; mi < 4; ++mi) af[mi] = fragld(A, wy + mi * 16 + fr, ks * 4 + fq);
#pragma unroll
            for (int ni = 0; ni < 4; ++ni) bfv[ni] = fragld(Bm, wx + ni * 16 + fr, ks * 4 + fq);
#pragma unroll
            for (int mi = 0; mi < 4; ++mi)
#pragma unroll
                for (int ni = 0; ni < 4; ++ni)
                    acc[mi][ni] = MFMA16(af[mi], bfv[ni], acc[mi][ni]);
        }
        if (i + 1 < 16) { WAITL0; WAITV(0); BARRIER; }
    }
#pragma unroll
    for (int mi = 0; mi < 4; ++mi)
#pragma unroll
        for (int ni = 0; ni < 4; ++ni) {
            const int col = n0 + wx + ni * 16 + fr;
            const float b = cbig[col];
#pragma unroll
            for (int j = 0; j < 4; ++j) {
                const size_t row = m0 + wy + mi * 16 + fq * 4 + j;
                XBIG[row * 10240 + col] = f2bf(acc[mi][ni][j] + b);
            }
        }
}

// ---------------- tier0 per-step: qkv+gupd = h @ wbigH + XBIG_t ----------------
// NO LDS, NO barriers: both MFMA operand fragments are per-lane 16B loads
// straight from global (h is L2-hot, wbigH is L2/L3-hot; staging was pure
// overhead).  High occupancy + free compiler pipelining hide latency.
__global__ __launch_bounds__(256, 4) void k_qg(
    const unsigned short* __restrict__ hxbf,
    const unsigned short* __restrict__ wbigH,
    const unsigned short* __restrict__ XBIGt,   // [256][10240]
    unsigned short* __restrict__ qkvbf,
    float* __restrict__ gupd) {
    const int tid = threadIdx.x, lane = tid & 63, wave = tid >> 6;
    const int n0 = blockIdx.x * 64, b0 = blockIdx.y * 32;
    const int wr = (wave & 1) * 16, wc = (wave >> 1) * 32;
    const int fr = lane & 15, fq = lane >> 4;
    f4 acc[2] = {};

    const unsigned short* arow = hxbf + (size_t)(b0 + wr + fr) * 1024 + fq * 8;
    const unsigned short* brow0 = wbigH + (size_t)(n0 + wc + fr) * 1024 + fq * 8;
    const unsigned short* brow1 = wbigH + (size_t)(n0 + wc + 16 + fr) * 1024 + fq * 8;
#pragma unroll
    for (int i = 0; i < 32; ++i) {
        const int ko = i * 32;
        bf8 a0 = *(const bf8*)(arow + ko);
        bf8 b0v = *(const bf8*)(brow0 + ko);
        bf8 b1v = *(const bf8*)(brow1 + ko);
        acc[0] = MFMA16(a0, b0v, acc[0]);
        acc[1] = MFMA16(a0, b1v, acc[1]);
    }
#pragma unroll
    for (int ni = 0; ni < 2; ++ni) {
        const int col = n0 + wc + ni * 16 + fr;
        const int seg = col >> 10, d = col & 1023;
#pragma unroll
        for (int j = 0; j < 4; ++j) {
            const int row = b0 + wr + fq * 4 + j;
            const float v = acc[ni][j] + bf2f(XBIGt[(size_t)row * 10240 + col]);
            if (seg == 9) {
                gupd[(size_t)row * 1024 + d] = tanhf(v);
            } else {
                const int gp = seg / 3, which = seg % 3;
                qkvbf[((size_t)gp * NB + row) * 3072 + which * 1024 + d] = f2bf(v);
            }
        }
    }
}

// ---------------- fallback per-step S1 (staged, proven) ----------------
__global__ __launch_bounds__(256, 2) void k_pre(
    const unsigned short* __restrict__ hxbf,
    const unsigned short* __restrict__ xt,
    const unsigned short* __restrict__ wgT,
    const float* __restrict__ bg,
    unsigned short* __restrict__ prebf,
    float* __restrict__ gupd) {
    __shared__ unsigned short sA[4][32 * 64];
    __shared__ unsigned short sB[4][64 * 64];
    const int tid = threadIdx.x, lane = tid & 63, wave = tid >> 6;
    const int n0 = blockIdx.x * 64, b0 = blockIdx.y * 32;
    const int wr = (wave & 1) * 16, wc = (wave >> 1) * 32;
    const int fr = lane & 15, fq = lane >> 4;
    constexpr int NT = 32;
    f4 acc[2] = {};

    const unsigned short* hb = hxbf + (size_t)b0 * 1024;
    const unsigned short* xb = xt + (size_t)b0 * 1024;
    auto asrc = [&](int i) -> const unsigned short* {
        return i < 16 ? xb + i * 64 : hb + (i - 16) * 64;
    };
    auto bsrc = [&](int i) -> const unsigned short* {
        return wgT + (size_t)n0 * 2048 + i * 64;
    };

#pragma unroll
    for (int p = 0; p < 3; ++p) {
        stage64<32>(asrc(p), 1024, sA[p], wave, lane);
        stage64<64>(bsrc(p), 2048, sB[p], wave, lane);
    }
    WAITV(6); BARRIER;
#pragma unroll
    for (int i = 0; i < NT; ++i) {
        if (i + 3 < NT) {
            stage64<32>(asrc(i + 3), 1024, sA[(i + 3) & 3], wave, lane);
            stage64<64>(bsrc(i + 3), 2048, sB[(i + 3) & 3], wave, lane);
        }
        const unsigned short* A = sA[i & 3];
        const unsigned short* Bm = sB[i & 3];
#pragma unroll
        for (int ks = 0; ks < 2; ++ks) {
            bf8 a0 = fragld(A, wr + fr, ks * 4 + fq);
            bf8 b0v = fragld(Bm, wc + fr, ks * 4 + fq);
            bf8 b1v = fragld(Bm, wc + 16 + fr, ks * 4 + fq);
            acc[0] = MFMA16(a0, b0v, acc[0]);
            acc[1] = MFMA16(a0, b1v, acc[1]);
        }
        if (i < NT - 1) {
            WAITL0;
            if (i + 3 < NT) { WAITV(6); }
            else if (i + 2 < NT) { WAITV(3); }
            else { WAITV(0); }
            BARRIER;
        }
    }
#pragma unroll
    for (int ni = 0; ni < 2; ++ni) {
        const int col = n0 + wc + ni * 16 + fr;
        const int gg = col >> 10, d = col & 1023;
#pragma unroll
        for (int j = 0; j < 4; ++j) {
            const int row = b0 + wr + fq * 4 + j;
            float v = acc[ni][j] + bg[col];
            if (gg == 2) {
                gupd[(size_t)row * 1024 + d] = tanhf(v);
            } else {
                const int gm = (gg == 3) ? 2 : gg;
                prebf[((size_t)gm * NB + row) * 1024 + d] = f2bf(v);
            }
        }
    }
}

// ---------------- fallback per-step S2: direct-fragment, no LDS ----------------
__global__ __launch_bounds__(256, 4) void k_qkv(
    const unsigned short* __restrict__ prebf,
    const unsigned short* __restrict__ wqkvT,
    const float* __restrict__ bq,
    const float* __restrict__ bk,
    const float* __restrict__ bv,
    unsigned short* __restrict__ qkvbf) {
    const int tid = threadIdx.x, lane = tid & 63, wave = tid >> 6;
    const int g = blockIdx.z;
    const int n0 = blockIdx.x * 64, b0 = blockIdx.y * 32;
    const int wr = (wave & 1) * 16, wc = (wave >> 1) * 32;
    const int fr = lane & 15, fq = lane >> 4;
    f4 acc[2] = {};

    const unsigned short* arow = prebf + ((size_t)g * NB + b0 + wr + fr) * 1024 + fq * 8;
    const unsigned short* brow0 = wqkvT + ((size_t)g * 3072 + n0 + wc + fr) * 1024 + fq * 8;
    const unsigned short* brow1 = wqkvT + ((size_t)g * 3072 + n0 + wc + 16 + fr) * 1024 + fq * 8;
#pragma unroll
    for (int i = 0; i < 32; ++i) {
        const int ko = i * 32;
        bf8 a0 = *(const bf8*)(arow + ko);
        bf8 b0v = *(const bf8*)(brow0 + ko);
        bf8 b1v = *(const bf8*)(brow1 + ko);
        acc[0] = MFMA16(a0, b0v, acc[0]);
        acc[1] = MFMA16(a0, b1v, acc[1]);
    }
#pragma unroll
    for (int ni = 0; ni < 2; ++ni) {
        const int col = n0 + wc + ni * 16 + fr;
        const int which = col >> 10, d = col & 1023;
        const float* bp = which == 0 ? bq : (which == 1 ? bk : bv);
        const float bias = bp[g * 1024 + d];
#pragma unroll
        for (int j = 0; j < 4; ++j) {
            const int row = b0 + wr + fq * 4 + j;
            qkvbf[((size_t)g * NB + row) * 3072 + col] = f2bf(acc[ni][j] + bias);
        }
    }
}

// ---------------- per-step S3: cross-head attention, one WG per (batch, gate) ----------------
__global__ __launch_bounds__(256) void k_attn(const unsigned short* __restrict__ qkvbf,
                                              unsigned short* __restrict__ aobf) {
    __shared__ unsigned short qs[16][72], ksm[16][72], vsm[16][72];
    __shared__ float aw[16][17];
    const int b = blockIdx.x, g = blockIdx.y, tid = threadIdx.x;
    const unsigned short* src = qkvbf + ((size_t)g * NB + b) * 3072;
#pragma unroll
    for (int j = 0; j < 3; ++j) {
        const int n = (j * 256 + tid) * 4;
        us4 dv = *(const us4*)(src + n);
        const int part = n >> 10, h = (n >> 6) & 15, c = n & 63;
        unsigned short* dst = part == 0 ? &qs[h][c] : (part == 1 ? &ksm[h][c] : &vsm[h][c]);
        *(us4*)dst = dv;
    }
    __syncthreads();
    const int h = tid >> 4, kp = tid & 15;
    float s = 0.f;
#pragma unroll
    for (int dblk = 0; dblk < 8; ++dblk) {
        us8 qv = *(const us8*)&qs[h][dblk * 8];
        us8 kv = *(const us8*)&ksm[kp][dblk * 8];
#pragma unroll
        for (int e = 0; e < 8; ++e) s += bf2f(qv[e]) * bf2f(kv[e]);
    }
    s *= 0.125f;
    float m = s;
#pragma unroll
    for (int off = 8; off; off >>= 1) m = fmaxf(m, __shfl_xor(m, off, 16));
    const float p = __expf(s - m);
    float sum = p;
#pragma unroll
    for (int off = 8; off; off >>= 1) sum += __shfl_xor(sum, off, 16);
    aw[h][kp] = p / sum;
    __syncthreads();
    float a0 = 0.f, a1 = 0.f, a2 = 0.f, a3 = 0.f;
#pragma unroll
    for (int kk = 0; kk < 16; ++kk) {
        const float w = aw[h][kk];
        us4 vv = *(const us4*)&vsm[kk][kp * 4];
        a0 += w * bf2f(vv[0]); a1 += w * bf2f(vv[1]);
        a2 += w * bf2f(vv[2]); a3 += w * bf2f(vv[3]);
    }
    us4 ov;
    ov[0] = f2bf(a0); ov[1] = f2bf(a1); ov[2] = f2bf(a2); ov[3] = f2bf(a3);
    *(us4*)(aobf + ((size_t)g * NB + b) * 1024 + h * 64 + kp * 4) = ov;
}

// ---------------- per-step S4: direct-fragment, no LDS; 3 gate GEMMs + cell update ----------------
__global__ __launch_bounds__(256, 4) void k_gate(
    const unsigned short* __restrict__ aobf,
    const unsigned short* __restrict__ woT,
    const float* __restrict__ bo,
    const float* __restrict__ gupd,
    unsigned short* __restrict__ hxbf,
    float* __restrict__ out, int t) {
    const int tid = threadIdx.x, lane = tid & 63, wave = tid >> 6;
    const int d0 = blockIdx.x * 32, b0 = blockIdx.y * 32;
    const int wr = (wave & 1) * 16, wc = (wave >> 1) * 16;
    const int fr = lane & 15, fq = lane >> 4;
    f4 acc[3] = {};

    const unsigned short* ar0 = aobf + ((size_t)0 * NB + b0 + wr + fr) * 1024 + fq * 8;
    const unsigned short* ar1 = aobf + ((size_t)1 * NB + b0 + wr + fr) * 1024 + fq * 8;
    const unsigned short* ar2 = aobf + ((size_t)2 * NB + b0 + wr + fr) * 1024 + fq * 8;
    const unsigned short* br0 = woT + ((size_t)0 * 1024 + d0 + wc + fr) * 1024 + fq * 8;
    const unsigned short* br1 = woT + ((size_t)1 * 1024 + d0 + wc + fr) * 1024 + fq * 8;
    const unsigned short* br2 = woT + ((size_t)2 * 1024 + d0 + wc + fr) * 1024 + fq * 8;
#pragma unroll
    for (int i = 0; i < 32; ++i) {
        const int ko = i * 32;
        acc[0] = MFMA16(*(const bf8*)(ar0 + ko), *(const bf8*)(br0 + ko), acc[0]);
        acc[1] = MFMA16(*(const bf8*)(ar1 + ko), *(const bf8*)(br1 + ko), acc[1]);
        acc[2] = MFMA16(*(const bf8*)(ar2 + ko), *(const bf8*)(br2 + ko), acc[2]);
    }

    const int col = d0 + wc + fr;
    const float bof = bo[col], boi = bo[1024 + col], boo = bo[2048 + col];
    float* cxp = out + OUT_CX_OFF;
    float* hxp = out + OUT_HX_OFF;
    float* outs = out + (size_t)t * NB * 1024;
#pragma unroll
    for (int j = 0; j < 4; ++j) {
        const int row = b0 + wr + fq * 4 + j;
        const size_t idx = (size_t)row * 1024 + col;
        const float fg = sigm(acc[0][j] + bof);
        const float ig = sigm(acc[1][j] + boi);
        const float og = sigm(acc[2][j] + boo);
        const float c = fg * cxp[idx] + ig * gupd[idx];
        const float h = og * tanhf(c);
        cxp[idx] = c;
        hxp[idx] = h;
        outs[idx] = h;
        hxbf[idx] = f2bf(h);
    }
}

extern "C" void kernel_launch(void* const* d_in, const int* in_sizes, int n_in,
                              void* d_out, int out_size, void* d_ws, size_t ws_size,
                              hipStream_t stream) {
    const float* inputs = (const float*)d_in[0];
    const float* Wg = (const float*)d_in[1];
    const float* bg = (const float*)d_in[2];
    const float* Wq = (const float*)d_in[3];
    const float* bq = (const float*)d_in[4];
    const float* Wk = (const float*)d_in[5];
    const float* bk = (const float*)d_in[6];
    const float* Wv = (const float*)d_in[7];
    const float* bv = (const float*)d_in[8];
    const float* Wo = (const float*)d_in[9];
    const float* bo = (const float*)d_in[10];
    float* out = (float*)d_out;
    (void)in_sizes; (void)n_in; (void)out_size;

    char* ws = (char*)d_ws;
    size_t off = 0;
    auto alloc = [&](size_t bytes) -> void* {
        void* p = ws + off;
        off += (bytes + 255) & ~(size_t)255;
        return p;
    };
    unsigned short* wgT   = (unsigned short*)alloc((size_t)4096 * 2048 * 2);
    unsigned short* wqkvT = (unsigned short*)alloc((size_t)3 * 3072 * 1024 * 2);
    unsigned short* woT   = (unsigned short*)alloc((size_t)3 * 1024 * 1024 * 2);
    unsigned short* wgnt  = (unsigned short*)alloc((size_t)4 * 2048 * 1024 * 2);
    unsigned short* hxbf  = (unsigned short*)alloc((size_t)256 * 1024 * 2);
    unsigned short* prebf = (unsigned short*)alloc((size_t)3 * 256 * 1024 * 2);
    float*          gupd  = (float*)alloc((size_t)256 * 1024 * 4);
    unsigned short* qkvbf = (unsigned short*)alloc((size_t)3 * 256 * 3072 * 2);
    unsigned short* aobf  = (unsigned short*)alloc((size_t)3 * 256 * 1024 * 2);
    unsigned short* xbfs  = (unsigned short*)alloc((size_t)2 * 256 * 1024 * 2);
    const size_t off_base = off;
    unsigned short* xbf   = (unsigned short*)alloc((size_t)65536 * 1024 * 2);
    const size_t off_xbf = off;
    unsigned short* wbigX = (unsigned short*)alloc((size_t)10240 * 1024 * 2);
    unsigned short* wbigH = (unsigned short*)alloc((size_t)10240 * 1024 * 2);
    float*          cbig  = (float*)alloc((size_t)10240 * 4);
    const size_t off_wb = off;
    unsigned short* XBIGc = (unsigned short*)(ws + off_wb);

    int CH = 0;
    for (int c = 64; c >= 4; c >>= 1) {
        if (ws_size >= off_wb + (size_t)c * 256 * 10240 * 2) { CH = c; break; }
    }
    int tier;
    if (CH > 0) tier = 0;
    else if (ws_size >= off_xbf) tier = 2;
    else if (ws_size >= off_base) tier = 3;
    else return;

    hipMemsetAsync(hxbf, 0, (size_t)256 * 1024 * 2, stream);
    hipMemsetAsync(out + OUT_CX_OFF, 0, (size_t)256 * 1024 * 4, stream);

    // one-time weight convert+transpose (all tiers)
    for (int g = 0; g < 4; ++g)
        k_transpose<<<dim3(32, 64), 256, 0, stream>>>(
            Wg + (size_t)g * 2048 * 1024, wgT + (size_t)g * 1024 * 2048, 2048, 1024);
    const float* wsrc[3] = {Wq, Wk, Wv};
    for (int g = 0; g < 3; ++g)
        for (int wi = 0; wi < 3; ++wi)
            k_transpose<<<dim3(32, 32), 256, 0, stream>>>(
                wsrc[wi] + (size_t)g * 1024 * 1024,
                wqkvT + (size_t)g * 3072 * 1024 + (size_t)wi * 1024 * 1024, 1024, 1024);
    for (int g = 0; g < 3; ++g)
        k_transpose<<<dim3(32, 32), 256, 0, stream>>>(
            Wo + (size_t)g * 1024 * 1024, woT + (size_t)g * 1024 * 1024, 1024, 1024);

    if (tier <= 2) k_x2bf<<<2048, 256, 0, stream>>>(inputs, xbf, 16777216);

    if (tier == 0) {
        k_x2bf<<<2048, 256, 0, stream>>>(Wg, wgnt, 2097152);
        k_wfz<<<dim3(8, 8, 18), 256, 0, stream>>>(wqkvT, wgnt, wbigX, wbigH);
        k_seg9<<<1024, 256, 0, stream>>>(wgT, wbigX, wbigH);
        k_cbig<<<40, 256, 0, stream>>>(bg, Wq, Wk, Wv, bq, bk, bv, cbig);

        for (int c = 0; c < 256 / CH; ++c) {
            k_xbig<<<dim3(80, CH * 2), 256, 0, stream>>>(
                xbf + (size_t)c * CH * 256 * 1024, wbigX, cbig, XBIGc);
            for (int tl = 0; tl < CH; ++tl) {
                const int t = c * CH + tl;
                k_qg<<<dim3(160, 8), 256, 0, stream>>>(
                    hxbf, wbigH, XBIGc + (size_t)tl * 256 * 10240, qkvbf, gupd);
                k_attn<<<dim3(256, 3), 256, 0, stream>>>(qkvbf, aobf);
                k_gate<<<dim3(32, 8), 256, 0, stream>>>(aobf, woT, bo, gupd, hxbf, out, t);
            }
        }
    } else {
        for (int t = 0; t < 256; ++t) {
            if (tier == 3)
                k_x2bf<<<64, 256, 0, stream>>>(inputs + (size_t)t * 262144,
                                               xbfs + (size_t)(t & 1) * 262144, 65536);
            k_pre<<<dim3(64, 8), 256, 0, stream>>>(
                hxbf,
                tier == 2 ? xbf + (size_t)t * 262144 : xbfs + (size_t)(t & 1) * 262144,
                wgT, bg, prebf, gupd);
            k_qkv<<<dim3(48, 8, 3), 256, 0, stream>>>(prebf, wqkvT, bq, bk, bv, qkvbf);
            k_attn<<<dim3(256, 3), 256, 0, stream>>>(qkvbf, aobf);
            k_gate<<<dim3(32, 8), 256, 0, stream>>>(aobf, woT, bo, gupd, hxbf, out, t);
        }
    }
}

// Round 13
// 14803.096 us; speedup vs baseline: 1.6848x; 1.6848x over previous
//
#include <hip/hip_runtime.h>

typedef __attribute__((ext_vector_type(8))) short bf8;
typedef __attribute__((ext_vector_type(8))) unsigned short us8;
typedef __attribute__((ext_vector_type(4))) unsigned short us4;
typedef __attribute__((ext_vector_type(4))) float f4;

#define NB 256
#define OUT_HX_OFF ((size_t)256 * 256 * 1024)
#define OUT_CX_OFF (OUT_HX_OFF + (size_t)256 * 1024)

static __device__ __forceinline__ unsigned short f2bf(float f) {
    unsigned u = __builtin_bit_cast(unsigned, f);
    return (unsigned short)((u + 0x7FFFu + ((u >> 16) & 1u)) >> 16);
}
static __device__ __forceinline__ float bf2f(unsigned short h) {
    return __builtin_bit_cast(float, (unsigned)h << 16);
}
static __device__ __forceinline__ float sigm(float x) {
    return 1.0f / (1.0f + __expf(-x));
}

#define MFMA16(a, b, c) __builtin_amdgcn_mfma_f32_16x16x32_bf16(a, b, c, 0, 0, 0)

#define GLDS16(g, l)                                                        \
    __builtin_amdgcn_global_load_lds(                                       \
        (const __attribute__((address_space(1))) void*)(g),                 \
        (__attribute__((address_space(3))) void*)(l), 16, 0, 0)

#define WAITV(n) asm volatile("s_waitcnt vmcnt(" #n ")" ::: "memory")
#define WAITL0 asm volatile("s_waitcnt lgkmcnt(0)" ::: "memory")
#define BARRIER                                                             \
    do {                                                                    \
        __builtin_amdgcn_s_barrier();                                       \
        __builtin_amdgcn_sched_barrier(0);                                  \
    } while (0)

template <int R>
static __device__ __forceinline__ void stage64(const unsigned short* g, int gstride,
                                               unsigned short* lds, int wave, int lane) {
#pragma unroll
    for (int j = 0; j < R / 32; ++j) {
        const int seg = wave * (R / 32) + j;
        const int row = seg * 8 + (lane >> 3);
        const int chunk = (lane & 7) ^ (row & 7);
        GLDS16(g + (size_t)row * gstride + chunk * 8, lds + seg * 512);
    }
}

static __device__ __forceinline__ bf8 fragld(const unsigned short* lds, int row, int ck) {
    return *(const bf8*)&lds[row * 64 + (((ck) ^ (row & 7)) << 3)];
}

// ---------------- one-time: f32 -> bf16 convert ----------------
__global__ __launch_bounds__(256) void k_x2bf(const float* __restrict__ src,
                                              unsigned short* __restrict__ dst, int n4) {
    const int stride = gridDim.x * 256;
    for (int i = blockIdx.x * 256 + threadIdx.x; i < n4; i += stride) {
        f4 v = ((const f4*)src)[i];
        us4 o;
        o[0] = f2bf(v[0]); o[1] = f2bf(v[1]); o[2] = f2bf(v[2]); o[3] = f2bf(v[3]);
        ((us4*)dst)[i] = o;
    }
}

// ---------------- one-time: weight transpose f32[K][N] -> bf16[N][K] ----------------
__global__ __launch_bounds__(256) void k_transpose(const float* __restrict__ src,
                                                   unsigned short* __restrict__ dst,
                                                   int K, int N) {
    __shared__ float tile[32][33];
    const int tx = threadIdx.x & 31, ty = threadIdx.x >> 5;
    const int n0 = blockIdx.x * 32, k0 = blockIdx.y * 32;
#pragma unroll
    for (int i = 0; i < 4; ++i) tile[ty + i * 8][tx] = src[(size_t)(k0 + ty + i * 8) * N + n0 + tx];
    __syncthreads();
#pragma unroll
    for (int i = 0; i < 4; ++i)
        dst[(size_t)(n0 + ty + i * 8) * K + k0 + tx] = f2bf(tile[tx][ty + i * 8]);
}

// ---------------- one-time: fused weights, all 18 products in one launch ----------------
__global__ __launch_bounds__(256) void k_wfz(const unsigned short* __restrict__ wqkvT,
                                             const unsigned short* __restrict__ wgnt,
                                             unsigned short* __restrict__ wbigX,
                                             unsigned short* __restrict__ wbigH) {
    __shared__ unsigned short sA[2][128 * 64];
    __shared__ unsigned short sB[2][128 * 64];
    const int tid = threadIdx.x, lane = tid & 63, wave = tid >> 6;
    const int z = blockIdx.z, j = z >> 1, xh = z & 1;
    const int gp = j / 3, which = j % 3;
    const int selg = (gp == 2) ? 3 : gp;
    const unsigned short* Aab = wqkvT + ((size_t)gp * 3072 + which * 1024) * 1024;
    const unsigned short* Bb = wgnt + (size_t)selg * 2048 * 1024 + (size_t)xh * 1024 * 1024;
    unsigned short* outp = (xh ? wbigH : wbigX) + (size_t)j * 1024 * 1024;
    const int n0 = blockIdx.x * 128, m0 = blockIdx.y * 128;
    const int wy = (wave >> 1) * 64, wx = (wave & 1) * 64;
    const int fr = lane & 15, fq = lane >> 4;
    f4 acc[4][4] = {};

    stage64<128>(Aab + (size_t)m0 * 1024, 1024, sA[0], wave, lane);
    stage64<128>(Bb + (size_t)n0 * 1024, 1024, sB[0], wave, lane);
    WAITV(0); BARRIER;
#pragma unroll
    for (int i = 0; i < 16; ++i) {
        if (i + 1 < 16) {
            stage64<128>(Aab + (size_t)m0 * 1024 + (i + 1) * 64, 1024, sA[(i + 1) & 1], wave, lane);
            stage64<128>(Bb + (size_t)n0 * 1024 + (i + 1) * 64, 1024, sB[(i + 1) & 1], wave, lane);
        }
        const unsigned short* A = sA[i & 1];
        const unsigned short* Bm = sB[i & 1];
#pragma unroll
        for (int ks = 0; ks < 2; ++ks) {
            bf8 af[4], bfv[4];
#pragma unroll
            for (int mi = 0; mi < 4; ++mi) af[mi] = fragld(A, wy + mi * 16 + fr, ks * 4 + fq);
#pragma unroll
            for (int ni = 0; ni < 4; ++ni) bfv[ni] = fragld(Bm, wx + ni * 16 + fr, ks * 4 + fq);
#pragma unroll
            for (int mi = 0; mi < 4; ++mi)
#pragma unroll
                for (int ni = 0; ni < 4; ++ni)
                    acc[mi][ni] = MFMA16(af[mi], bfv[ni], acc[mi][ni]);
        }
        if (i + 1 < 16) { WAITL0; WAITV(0); BARRIER; }
    }
#pragma unroll
    for (int mi = 0; mi < 4; ++mi)
#pragma unroll
        for (int ni = 0; ni < 4; ++ni) {
            const int col = n0 + wx + ni * 16 + fr;
#pragma unroll
            for (int j2 = 0; j2 < 4; ++j2) {
                const int row = m0 + wy + mi * 16 + fq * 4 + j2;
                outp[(size_t)row * 1024 + col] = f2bf(acc[mi][ni][j2]);
            }
        }
}

// ---------------- one-time: wbig segment 9 (gate-2 rows) from wgT ----------------
__global__ __launch_bounds__(256) void k_seg9(const unsigned short* __restrict__ wgT,
                                              unsigned short* __restrict__ wbigX,
                                              unsigned short* __restrict__ wbigH) {
    const int d = blockIdx.x, k4 = threadIdx.x * 4;
    us4 vx = *(const us4*)(wgT + (size_t)(2048 + d) * 2048 + k4);
    us4 vh = *(const us4*)(wgT + (size_t)(2048 + d) * 2048 + 1024 + k4);
    *(us4*)(wbigX + (size_t)(9216 + d) * 1024 + k4) = vx;
    *(us4*)(wbigH + (size_t)(9216 + d) * 1024 + k4) = vh;
}

// ---------------- one-time: cbig[n] = bg[g']@Wqkv + bqkv  (f32) ----------------
__global__ __launch_bounds__(256) void k_cbig(const float* __restrict__ bg,
                                              const float* __restrict__ Wq,
                                              const float* __restrict__ Wk,
                                              const float* __restrict__ Wv,
                                              const float* __restrict__ bq,
                                              const float* __restrict__ bk,
                                              const float* __restrict__ bv,
                                              float* __restrict__ cbig) {
    const int n = blockIdx.x * 256 + threadIdx.x;
    const int j = n >> 10, d = n & 1023;
    float s;
    if (j < 9) {
        const int gp = j / 3, which = j % 3;
        const int selg = (gp == 2) ? 3 : gp;
        const float* W = which == 0 ? Wq : (which == 1 ? Wk : Wv);
        const float* bqkv = which == 0 ? bq : (which == 1 ? bk : bv);
        s = bqkv[gp * 1024 + d];
        const float* wb = W + (size_t)gp * 1024 * 1024;
        const float* bgb = bg + selg * 1024;
        for (int k = 0; k < 1024; ++k) s += bgb[k] * wb[(size_t)k * 1024 + d];
    } else {
        s = bg[2048 + d];
    }
    cbig[n] = s;
}

// ---------------- chunked: XBIG = xbf_chunk @ wbigX^T + cbig ----------------
__global__ __launch_bounds__(256) void k_xbig(const unsigned short* __restrict__ xbf,
                                              const unsigned short* __restrict__ wbigX,
                                              const float* __restrict__ cbig,
                                              unsigned short* __restrict__ XBIG) {
    __shared__ unsigned short sA[2][128 * 64];
    __shared__ unsigned short sB[2][128 * 64];
    const int tid = threadIdx.x, lane = tid & 63, wave = tid >> 6;
    const int n0 = blockIdx.x * 128;
    const size_t m0 = (size_t)blockIdx.y * 128;
    const int wy = (wave >> 1) * 64, wx = (wave & 1) * 64;
    const int fr = lane & 15, fq = lane >> 4;
    f4 acc[4][4] = {};

    stage64<128>(xbf + m0 * 1024, 1024, sA[0], wave, lane);
    stage64<128>(wbigX + (size_t)n0 * 1024, 1024, sB[0], wave, lane);
    WAITV(0); BARRIER;
#pragma unroll
    for (int i = 0; i < 16; ++i) {
        if (i + 1 < 16) {
            stage64<128>(xbf + m0 * 1024 + (i + 1) * 64, 1024, sA[(i + 1) & 1], wave, lane);
            stage64<128>(wbigX + (size_t)n0 * 1024 + (i + 1) * 64, 1024, sB[(i + 1) & 1], wave, lane);
        }
        const unsigned short* A = sA[i & 1];
        const unsigned short* Bm = sB[i & 1];
#pragma unroll
        for (int ks = 0; ks < 2; ++ks) {
            bf8 af[4], bfv[4];
#pragma unroll
            for (int mi = 0; mi < 4; ++mi) af[mi] = fragld(A, wy + mi * 16 + fr, ks * 4 + fq);
#pragma unroll
            for (int ni = 0; ni < 4; ++ni) bfv[ni] = fragld(Bm, wx + ni * 16 + fr, ks * 4 + fq);
#pragma unroll
            for (int mi = 0; mi < 4; ++mi)
#pragma unroll
                for (int ni = 0; ni < 4; ++ni)
                    acc[mi][ni] = MFMA16(af[mi], bfv[ni], acc[mi][ni]);
        }
        if (i + 1 < 16) { WAITL0; WAITV(0); BARRIER; }
    }
#pragma unroll
    for (int mi = 0; mi < 4; ++mi)
#pragma unroll
        for (int ni = 0; ni < 4; ++ni) {
            const int col = n0 + wx + ni * 16 + fr;
            const float b = cbig[col];
#pragma unroll
            for (int j = 0; j < 4; ++j) {
                const size_t row = m0 + wy + mi * 16 + fq * 4 + j;
                XBIG[row * 10240 + col] = f2bf(acc[mi][ni][j] + b);
            }
        }
}

// ---------------- tier0 per-step: qkv+gupd = h @ wbigH + XBIG_t ----------------
// 64x64 tile, 640 blocks (3/CU at 48 KB LDS), depth-3 4-slot ring (vmcnt 8/4/0).
__global__ __launch_bounds__(256, 3) void k_qg(
    const unsigned short* __restrict__ hxbf,
    const unsigned short* __restrict__ wbigH,
    const unsigned short* __restrict__ XBIGt,   // [256][10240]
    unsigned short* __restrict__ qkvbf,
    float* __restrict__ gupd) {
    __shared__ unsigned short sA[4][64 * 64];   // 32 KB (3 of 4 slots used deep)
    __shared__ unsigned short sB[4][64 * 64];
    const int tid = threadIdx.x, lane = tid & 63, wave = tid >> 6;
    const int n0 = blockIdx.x * 64, b0 = blockIdx.y * 64;
    const unsigned short* Aab = hxbf + (size_t)b0 * 1024;
    const unsigned short* Bb = wbigH + (size_t)n0 * 1024;
    const int wy = (wave >> 1) * 32, wx = (wave & 1) * 32;
    const int fr = lane & 15, fq = lane >> 4;
    f4 acc[2][2] = {};

#pragma unroll
    for (int p = 0; p < 3; ++p) {
        stage64<64>(Aab + p * 64, 1024, sA[p], wave, lane);
        stage64<64>(Bb + p * 64, 1024, sB[p], wave, lane);
    }
    WAITV(8); BARRIER;
#pragma unroll
    for (int i = 0; i < 16; ++i) {
        if (i + 3 < 16) {
            stage64<64>(Aab + (i + 3) * 64, 1024, sA[(i + 3) & 3], wave, lane);
            stage64<64>(Bb + (i + 3) * 64, 1024, sB[(i + 3) & 3], wave, lane);
        }
        const unsigned short* A = sA[i & 3];
        const unsigned short* Bm = sB[i & 3];
#pragma unroll
        for (int ks = 0; ks < 2; ++ks) {
            bf8 af[2], bfv[2];
#pragma unroll
            for (int mi = 0; mi < 2; ++mi) af[mi] = fragld(A, wy + mi * 16 + fr, ks * 4 + fq);
#pragma unroll
            for (int ni = 0; ni < 2; ++ni) bfv[ni] = fragld(Bm, wx + ni * 16 + fr, ks * 4 + fq);
#pragma unroll
            for (int mi = 0; mi < 2; ++mi)
#pragma unroll
                for (int ni = 0; ni < 2; ++ni)
                    acc[mi][ni] = MFMA16(af[mi], bfv[ni], acc[mi][ni]);
        }
        if (i < 15) {
            WAITL0;
            if (i + 3 < 16) { WAITV(8); }
            else if (i + 2 < 16) { WAITV(4); }
            else { WAITV(0); }
            BARRIER;
        }
    }
#pragma unroll
    for (int mi = 0; mi < 2; ++mi)
#pragma unroll
        for (int ni = 0; ni < 2; ++ni) {
            const int col = n0 + wx + ni * 16 + fr;
            const int seg = col >> 10, d = col & 1023;
#pragma unroll
            for (int j = 0; j < 4; ++j) {
                const int row = b0 + wy + mi * 16 + fq * 4 + j;
                const float v = acc[mi][ni][j] + bf2f(XBIGt[(size_t)row * 10240 + col]);
                if (seg == 9) {
                    gupd[(size_t)row * 1024 + d] = tanhf(v);
                } else {
                    const int gp = seg / 3, which = seg % 3;
                    qkvbf[((size_t)gp * NB + row) * 3072 + which * 1024 + d] = f2bf(v);
                }
            }
        }
}

// ---------------- fallback per-step S1 (staged, proven) ----------------
__global__ __launch_bounds__(256, 2) void k_pre(
    const unsigned short* __restrict__ hxbf,
    const unsigned short* __restrict__ xt,
    const unsigned short* __restrict__ wgT,
    const float* __restrict__ bg,
    unsigned short* __restrict__ prebf,
    float* __restrict__ gupd) {
    __shared__ unsigned short sA[4][32 * 64];
    __shared__ unsigned short sB[4][64 * 64];
    const int tid = threadIdx.x, lane = tid & 63, wave = tid >> 6;
    const int n0 = blockIdx.x * 64, b0 = blockIdx.y * 32;
    const int wr = (wave & 1) * 16, wc = (wave >> 1) * 32;
    const int fr = lane & 15, fq = lane >> 4;
    constexpr int NT = 32;
    f4 acc[2] = {};

    const unsigned short* hb = hxbf + (size_t)b0 * 1024;
    const unsigned short* xb = xt + (size_t)b0 * 1024;
    auto asrc = [&](int i) -> const unsigned short* {
        return i < 16 ? xb + i * 64 : hb + (i - 16) * 64;
    };
    auto bsrc = [&](int i) -> const unsigned short* {
        return wgT + (size_t)n0 * 2048 + i * 64;
    };

#pragma unroll
    for (int p = 0; p < 3; ++p) {
        stage64<32>(asrc(p), 1024, sA[p], wave, lane);
        stage64<64>(bsrc(p), 2048, sB[p], wave, lane);
    }
    WAITV(6); BARRIER;
#pragma unroll
    for (int i = 0; i < NT; ++i) {
        if (i + 3 < NT) {
            stage64<32>(asrc(i + 3), 1024, sA[(i + 3) & 3], wave, lane);
            stage64<64>(bsrc(i + 3), 2048, sB[(i + 3) & 3], wave, lane);
        }
        const unsigned short* A = sA[i & 3];
        const unsigned short* Bm = sB[i & 3];
#pragma unroll
        for (int ks = 0; ks < 2; ++ks) {
            bf8 a0 = fragld(A, wr + fr, ks * 4 + fq);
            bf8 b0v = fragld(Bm, wc + fr, ks * 4 + fq);
            bf8 b1v = fragld(Bm, wc + 16 + fr, ks * 4 + fq);
            acc[0] = MFMA16(a0, b0v, acc[0]);
            acc[1] = MFMA16(a0, b1v, acc[1]);
        }
        if (i < NT - 1) {
            WAITL0;
            if (i + 3 < NT) { WAITV(6); }
            else if (i + 2 < NT) { WAITV(3); }
            else { WAITV(0); }
            BARRIER;
        }
    }
#pragma unroll
    for (int ni = 0; ni < 2; ++ni) {
        const int col = n0 + wc + ni * 16 + fr;
        const int gg = col >> 10, d = col & 1023;
#pragma unroll
        for (int j = 0; j < 4; ++j) {
            const int row = b0 + wr + fq * 4 + j;
            float v = acc[ni][j] + bg[col];
            if (gg == 2) {
                gupd[(size_t)row * 1024 + d] = tanhf(v);
            } else {
                const int gm = (gg == 3) ? 2 : gg;
                prebf[((size_t)gm * NB + row) * 1024 + d] = f2bf(v);
            }
        }
    }
}

// ---------------- fallback per-step S2 (staged, proven) ----------------
__global__ __launch_bounds__(256, 3) void k_qkv(
    const unsigned short* __restrict__ prebf,
    const unsigned short* __restrict__ wqkvT,
    const float* __restrict__ bq,
    const float* __restrict__ bk,
    const float* __restrict__ bv,
    unsigned short* __restrict__ qkvbf) {
    __shared__ unsigned short sA[4][32 * 64];
    __shared__ unsigned short sB[4][64 * 64];
    const int tid = threadIdx.x, lane = tid & 63, wave = tid >> 6;
    const int g = blockIdx.z;
    const int n0 = blockIdx.x * 64, b0 = blockIdx.y * 32;
    const unsigned short* Aab = prebf + ((size_t)g * NB + b0) * 1024;
    const unsigned short* Bb = wqkvT + ((size_t)g * 3072 + n0) * 1024;
    const int wr = (wave & 1) * 16, wc = (wave >> 1) * 32;
    const int fr = lane & 15, fq = lane >> 4;
    f4 acc[2] = {};

#pragma unroll
    for (int p = 0; p < 3; ++p) {
        stage64<32>(Aab + p * 64, 1024, sA[p], wave, lane);
        stage64<64>(Bb + p * 64, 1024, sB[p], wave, lane);
    }
    WAITV(6); BARRIER;
#pragma unroll
    for (int i = 0; i < 16; ++i) {
        if (i + 3 < 16) {
            stage64<32>(Aab + (i + 3) * 64, 1024, sA[(i + 3) & 3], wave, lane);
            stage64<64>(Bb + (i + 3) * 64, 1024, sB[(i + 3) & 3], wave, lane);
        }
        const unsigned short* A = sA[i & 3];
        const unsigned short* Bm = sB[i & 3];
#pragma unroll
        for (int ks = 0; ks < 2; ++ks) {
            bf8 a0 = fragld(A, wr + fr, ks * 4 + fq);
            bf8 b0v = fragld(Bm, wc + fr, ks * 4 + fq);
            bf8 b1v = fragld(Bm, wc + 16 + fr, ks * 4 + fq);
            acc[0] = MFMA16(a0, b0v, acc[0]);
            acc[1] = MFMA16(a0, b1v, acc[1]);
        }
        if (i < 15) {
            WAITL0;
            if (i + 3 < 16) { WAITV(6); }
            else if (i + 2 < 16) { WAITV(3); }
            else { WAITV(0); }
            BARRIER;
        }
    }
#pragma unroll
    for (int ni = 0; ni < 2; ++ni) {
        const int col = n0 + wc + ni * 16 + fr;
        const int which = col >> 10, d = col & 1023;
        const float* bp = which == 0 ? bq : (which == 1 ? bk : bv);
        const float bias = bp[g * 1024 + d];
#pragma unroll
        for (int j = 0; j < 4; ++j) {
            const int row = b0 + wr + fq * 4 + j;
            qkvbf[((size_t)g * NB + row) * 3072 + col] = f2bf(acc[ni][j] + bias);
        }
    }
}

// ---------------- per-step S3: cross-head attention, one WG per (batch, gate) ----------------
__global__ __launch_bounds__(256) void k_attn(const unsigned short* __restrict__ qkvbf,
                                              unsigned short* __restrict__ aobf) {
    __shared__ unsigned short qs[16][72], ksm[16][72], vsm[16][72];
    __shared__ float aw[16][17];
    const int b = blockIdx.x, g = blockIdx.y, tid = threadIdx.x;
    const unsigned short* src = qkvbf + ((size_t)g * NB + b) * 3072;
#pragma unroll
    for (int j = 0; j < 3; ++j) {
        const int n = (j * 256 + tid) * 4;
        us4 dv = *(const us4*)(src + n);
        const int part = n >> 10, h = (n >> 6) & 15, c = n & 63;
        unsigned short* dst = part == 0 ? &qs[h][c] : (part == 1 ? &ksm[h][c] : &vsm[h][c]);
        *(us4*)dst = dv;
    }
    __syncthreads();
    const int h = tid >> 4, kp = tid & 15;
    float s = 0.f;
#pragma unroll
    for (int dblk = 0; dblk < 8; ++dblk) {
        us8 qv = *(const us8*)&qs[h][dblk * 8];
        us8 kv = *(const us8*)&ksm[kp][dblk * 8];
#pragma unroll
        for (int e = 0; e < 8; ++e) s += bf2f(qv[e]) * bf2f(kv[e]);
    }
    s *= 0.125f;
    float m = s;
#pragma unroll
    for (int off = 8; off; off >>= 1) m = fmaxf(m, __shfl_xor(m, off, 16));
    const float p = __expf(s - m);
    float sum = p;
#pragma unroll
    for (int off = 8; off; off >>= 1) sum += __shfl_xor(sum, off, 16);
    aw[h][kp] = p / sum;
    __syncthreads();
    float a0 = 0.f, a1 = 0.f, a2 = 0.f, a3 = 0.f;
#pragma unroll
    for (int kk = 0; kk < 16; ++kk) {
        const float w = aw[h][kk];
        us4 vv = *(const us4*)&vsm[kk][kp * 4];
        a0 += w * bf2f(vv[0]); a1 += w * bf2f(vv[1]);
        a2 += w * bf2f(vv[2]); a3 += w * bf2f(vv[3]);
    }
    us4 ov;
    ov[0] = f2bf(a0); ov[1] = f2bf(a1); ov[2] = f2bf(a2); ov[3] = f2bf(a3);
    *(us4*)(aobf + ((size_t)g * NB + b) * 1024 + h * 64 + kp * 4) = ov;
}

// ---------------- per-step S4: gates = sigmoid(ao @ Wo + bo); cell update (staged) ----------------
__global__ __launch_bounds__(256, 1) void k_gate(
    const unsigned short* __restrict__ aobf,
    const unsigned short* __restrict__ woT,
    const float* __restrict__ bo,
    const float* __restrict__ gupd,
    unsigned short* __restrict__ hxbf,
    float* __restrict__ out, int t) {
    __shared__ unsigned short sA[4][3][32 * 64];
    __shared__ unsigned short sB[4][3][32 * 64];
    const int tid = threadIdx.x, lane = tid & 63, wave = tid >> 6;
    const int d0 = blockIdx.x * 32, b0 = blockIdx.y * 32;
    const int wr = (wave & 1) * 16, wc = (wave >> 1) * 16;
    const int fr = lane & 15, fq = lane >> 4;
    f4 acc[3] = {};

    auto stage_all = [&](int i, int slot) {
#pragma unroll
        for (int g = 0; g < 3; ++g) {
            stage64<32>(aobf + ((size_t)g * NB + b0) * 1024 + i * 64, 1024,
                        sA[slot][g], wave, lane);
            stage64<32>(woT + ((size_t)g * 1024 + d0) * 1024 + i * 64, 1024,
                        sB[slot][g], wave, lane);
        }
    };

    stage_all(0, 0);
    stage_all(1, 1);
    stage_all(2, 2);
    WAITV(12); BARRIER;
#pragma unroll
    for (int i = 0; i < 16; ++i) {
        if (i + 3 < 16) stage_all(i + 3, (i + 3) & 3);
        const int sl = i & 3;
#pragma unroll
        for (int g = 0; g < 3; ++g) {
#pragma unroll
            for (int ks = 0; ks < 2; ++ks) {
                bf8 a0 = fragld(sA[sl][g], wr + fr, ks * 4 + fq);
                bf8 b0v = fragld(sB[sl][g], wc + fr, ks * 4 + fq);
                acc[g] = MFMA16(a0, b0v, acc[g]);
            }
        }
        if (i < 15) {
            WAITL0;
            if (i + 3 < 16) { WAITV(12); }
            else if (i + 2 < 16) { WAITV(6); }
            else { WAITV(0); }
            BARRIER;
        }
    }

    const int col = d0 + wc + fr;
    const float bof = bo[col], boi = bo[1024 + col], boo = bo[2048 + col];
    float* cxp = out + OUT_CX_OFF;
    float* hxp = out + OUT_HX_OFF;
    float* outs = out + (size_t)t * NB * 1024;
#pragma unroll
    for (int j = 0; j < 4; ++j) {
        const int row = b0 + wr + fq * 4 + j;
        const size_t idx = (size_t)row * 1024 + col;
        const float fg = sigm(acc[0][j] + bof);
        const float ig = sigm(acc[1][j] + boi);
        const float og = sigm(acc[2][j] + boo);
        const float c = fg * cxp[idx] + ig * gupd[idx];
        const float h = og * tanhf(c);
        cxp[idx] = c;
        hxp[idx] = h;
        outs[idx] = h;
        hxbf[idx] = f2bf(h);
    }
}

extern "C" void kernel_launch(void* const* d_in, const int* in_sizes, int n_in,
                              void* d_out, int out_size, void* d_ws, size_t ws_size,
                              hipStream_t stream) {
    const float* inputs = (const float*)d_in[0];
    const float* Wg = (const float*)d_in[1];
    const float* bg = (const float*)d_in[2];
    const float* Wq = (const float*)d_in[3];
    const float* bq = (const float*)d_in[4];
    const float* Wk = (const float*)d_in[5];
    const float* bk = (const float*)d_in[6];
    const float* Wv = (const float*)d_in[7];
    const float* bv = (const float*)d_in[8];
    const float* Wo = (const float*)d_in[9];
    const float* bo = (const float*)d_in[10];
    float* out = (float*)d_out;
    (void)in_sizes; (void)n_in; (void)out_size;

    char* ws = (char*)d_ws;
    size_t off = 0;
    auto alloc = [&](size_t bytes) -> void* {
        void* p = ws + off;
        off += (bytes + 255) & ~(size_t)255;
        return p;
    };
    unsigned short* wgT   = (unsigned short*)alloc((size_t)4096 * 2048 * 2);
    unsigned short* wqkvT = (unsigned short*)alloc((size_t)3 * 3072 * 1024 * 2);
    unsigned short* woT   = (unsigned short*)alloc((size_t)3 * 1024 * 1024 * 2);
    unsigned short* wgnt  = (unsigned short*)alloc((size_t)4 * 2048 * 1024 * 2);
    unsigned short* hxbf  = (unsigned short*)alloc((size_t)256 * 1024 * 2);
    unsigned short* prebf = (unsigned short*)alloc((size_t)3 * 256 * 1024 * 2);
    float*          gupd  = (float*)alloc((size_t)256 * 1024 * 4);
    unsigned short* qkvbf = (unsigned short*)alloc((size_t)3 * 256 * 3072 * 2);
    unsigned short* aobf  = (unsigned short*)alloc((size_t)3 * 256 * 1024 * 2);
    unsigned short* xbfs  = (unsigned short*)alloc((size_t)2 * 256 * 1024 * 2);
    const size_t off_base = off;
    unsigned short* xbf   = (unsigned short*)alloc((size_t)65536 * 1024 * 2);
    const size_t off_xbf = off;
    unsigned short* wbigX = (unsigned short*)alloc((size_t)10240 * 1024 * 2);
    unsigned short* wbigH = (unsigned short*)alloc((size_t)10240 * 1024 * 2);
    float*          cbig  = (float*)alloc((size_t)10240 * 4);
    const size_t off_wb = off;
    unsigned short* XBIGc = (unsigned short*)(ws + off_wb);

    int CH = 0;
    for (int c = 64; c >= 4; c >>= 1) {
        if (ws_size >= off_wb + (size_t)c * 256 * 10240 * 2) { CH = c; break; }
    }
    int tier;
    if (CH > 0) tier = 0;
    else if (ws_size >= off_xbf) tier = 2;
    else if (ws_size >= off_base) tier = 3;
    else return;

    hipMemsetAsync(hxbf, 0, (size_t)256 * 1024 * 2, stream);
    hipMemsetAsync(out + OUT_CX_OFF, 0, (size_t)256 * 1024 * 4, stream);

    // one-time weight convert+transpose (all tiers)
    for (int g = 0; g < 4; ++g)
        k_transpose<<<dim3(32, 64), 256, 0, stream>>>(
            Wg + (size_t)g * 2048 * 1024, wgT + (size_t)g * 1024 * 2048, 2048, 1024);
    const float* wsrc[3] = {Wq, Wk, Wv};
    for (int g = 0; g < 3; ++g)
        for (int wi = 0; wi < 3; ++wi)
            k_transpose<<<dim3(32, 32), 256, 0, stream>>>(
                wsrc[wi] + (size_t)g * 1024 * 1024,
                wqkvT + (size_t)g * 3072 * 1024 + (size_t)wi * 1024 * 1024, 1024, 1024);
    for (int g = 0; g < 3; ++g)
        k_transpose<<<dim3(32, 32), 256, 0, stream>>>(
            Wo + (size_t)g * 1024 * 1024, woT + (size_t)g * 1024 * 1024, 1024, 1024);

    if (tier <= 2) k_x2bf<<<2048, 256, 0, stream>>>(inputs, xbf, 16777216);

    if (tier == 0) {
        k_x2bf<<<2048, 256, 0, stream>>>(Wg, wgnt, 2097152);
        k_wfz<<<dim3(8, 8, 18), 256, 0, stream>>>(wqkvT, wgnt, wbigX, wbigH);
        k_seg9<<<1024, 256, 0, stream>>>(wgT, wbigX, wbigH);
        k_cbig<<<40, 256, 0, stream>>>(bg, Wq, Wk, Wv, bq, bk, bv, cbig);

        for (int c = 0; c < 256 / CH; ++c) {
            k_xbig<<<dim3(80, CH * 2), 256, 0, stream>>>(
                xbf + (size_t)c * CH * 256 * 1024, wbigX, cbig, XBIGc);
            for (int tl = 0; tl < CH; ++tl) {
                const int t = c * CH + tl;
                k_qg<<<dim3(160, 4), 256, 0, stream>>>(
                    hxbf, wbigH, XBIGc + (size_t)tl * 256 * 10240, qkvbf, gupd);
                k_attn<<<dim3(256, 3), 256, 0, stream>>>(qkvbf, aobf);
                k_gate<<<dim3(32, 8), 256, 0, stream>>>(aobf, woT, bo, gupd, hxbf, out, t);
            }
        }
    } else {
        for (int t = 0; t < 256; ++t) {
            if (tier == 3)
                k_x2bf<<<64, 256, 0, stream>>>(inputs + (size_t)t * 262144,
                                               xbfs + (size_t)(t & 1) * 262144, 65536);
            k_pre<<<dim3(64, 8), 256, 0, stream>>>(
                hxbf,
                tier == 2 ? xbf + (size_t)t * 262144 : xbfs + (size_t)(t & 1) * 262144,
                wgT, bg, prebf, gupd);
            k_qkv<<<dim3(48, 8, 3), 256, 0, stream>>>(prebf, wqkvT, bq, bk, bv, qkvbf);
            k_attn<<<dim3(256, 3), 256, 0, stream>>>(qkvbf, aobf);
            k_gate<<<dim3(32, 8), 256, 0, stream>>>(aobf, woT, bo, gupd, hxbf, out, t);
        }
    }
}

// Round 14
// 12889.342 us; speedup vs baseline: 1.9350x; 1.1485x over previous
//
#include <hip/hip_runtime.h>

typedef __attribute__((ext_vector_type(8))) short bf8;
typedef __attribute__((ext_vector_type(8))) unsigned short us8;
typedef __attribute__((ext_vector_type(4))) unsigned short us4;
typedef __attribute__((ext_vector_type(4))) float f4;

#define NB 256
#define OUT_HX_OFF ((size_t)256 * 256 * 1024)
#define OUT_CX_OFF (OUT_HX_OFF + (size_t)256 * 1024)

static __device__ __forceinline__ unsigned short f2bf(float f) {
    unsigned u = __builtin_bit_cast(unsigned, f);
    return (unsigned short)((u + 0x7FFFu + ((u >> 16) & 1u)) >> 16);
}
static __device__ __forceinline__ float bf2f(unsigned short h) {
    return __builtin_bit_cast(float, (unsigned)h << 16);
}
static __device__ __forceinline__ float sigm(float x) {
    return 1.0f / (1.0f + __expf(-x));
}

#define MFMA16(a, b, c) __builtin_amdgcn_mfma_f32_16x16x32_bf16(a, b, c, 0, 0, 0)

#define GLDS16(g, l)                                                        \
    __builtin_amdgcn_global_load_lds(                                       \
        (const __attribute__((address_space(1))) void*)(g),                 \
        (__attribute__((address_space(3))) void*)(l), 16, 0, 0)

#define WAITV(n) asm volatile("s_waitcnt vmcnt(" #n ")" ::: "memory")
#define WAITL0 asm volatile("s_waitcnt lgkmcnt(0)" ::: "memory")
#define BARRIER                                                             \
    do {                                                                    \
        __builtin_amdgcn_s_barrier();                                       \
        __builtin_amdgcn_sched_barrier(0);                                  \
    } while (0)

template <int R>
static __device__ __forceinline__ void stage64(const unsigned short* g, int gstride,
                                               unsigned short* lds, int wave, int lane) {
#pragma unroll
    for (int j = 0; j < R / 32; ++j) {
        const int seg = wave * (R / 32) + j;
        const int row = seg * 8 + (lane >> 3);
        const int chunk = (lane & 7) ^ (row & 7);
        GLDS16(g + (size_t)row * gstride + chunk * 8, lds + seg * 512);
    }
}

static __device__ __forceinline__ bf8 fragld(const unsigned short* lds, int row, int ck) {
    return *(const bf8*)&lds[row * 64 + (((ck) ^ (row & 7)) << 3)];
}

// ---------------- one-time: f32 -> bf16 convert ----------------
__global__ __launch_bounds__(256) void k_x2bf(const float* __restrict__ src,
                                              unsigned short* __restrict__ dst, int n4) {
    const int stride = gridDim.x * 256;
    for (int i = blockIdx.x * 256 + threadIdx.x; i < n4; i += stride) {
        f4 v = ((const f4*)src)[i];
        us4 o;
        o[0] = f2bf(v[0]); o[1] = f2bf(v[1]); o[2] = f2bf(v[2]); o[3] = f2bf(v[3]);
        ((us4*)dst)[i] = o;
    }
}

// ---------------- one-time: weight transpose f32[K][N] -> bf16[N][K] ----------------
__global__ __launch_bounds__(256) void k_transpose(const float* __restrict__ src,
                                                   unsigned short* __restrict__ dst,
                                                   int K, int N) {
    __shared__ float tile[32][33];
    const int tx = threadIdx.x & 31, ty = threadIdx.x >> 5;
    const int n0 = blockIdx.x * 32, k0 = blockIdx.y * 32;
#pragma unroll
    for (int i = 0; i < 4; ++i) tile[ty + i * 8][tx] = src[(size_t)(k0 + ty + i * 8) * N + n0 + tx];
    __syncthreads();
#pragma unroll
    for (int i = 0; i < 4; ++i)
        dst[(size_t)(n0 + ty + i * 8) * K + k0 + tx] = f2bf(tile[tx][ty + i * 8]);
}

// ---------------- one-time: fused weights, all 18 products in one launch ----------------
__global__ __launch_bounds__(256) void k_wfz(const unsigned short* __restrict__ wqkvT,
                                             const unsigned short* __restrict__ wgnt,
                                             unsigned short* __restrict__ wbigX,
                                             unsigned short* __restrict__ wbigH) {
    __shared__ unsigned short sA[2][128 * 64];
    __shared__ unsigned short sB[2][128 * 64];
    const int tid = threadIdx.x, lane = tid & 63, wave = tid >> 6;
    const int z = blockIdx.z, j = z >> 1, xh = z & 1;
    const int gp = j / 3, which = j % 3;
    const int selg = (gp == 2) ? 3 : gp;
    const unsigned short* Aab = wqkvT + ((size_t)gp * 3072 + which * 1024) * 1024;
    const unsigned short* Bb = wgnt + (size_t)selg * 2048 * 1024 + (size_t)xh * 1024 * 1024;
    unsigned short* outp = (xh ? wbigH : wbigX) + (size_t)j * 1024 * 1024;
    const int n0 = blockIdx.x * 128, m0 = blockIdx.y * 128;
    const int wy = (wave >> 1) * 64, wx = (wave & 1) * 64;
    const int fr = lane & 15, fq = lane >> 4;
    f4 acc[4][4] = {};

    stage64<128>(Aab + (size_t)m0 * 1024, 1024, sA[0], wave, lane);
    stage64<128>(Bb + (size_t)n0 * 1024, 1024, sB[0], wave, lane);
    WAITV(0); BARRIER;
#pragma unroll
    for (int i = 0; i < 16; ++i) {
        if (i + 1 < 16) {
            stage64<128>(Aab + (size_t)m0 * 1024 + (i + 1) * 64, 1024, sA[(i + 1) & 1], wave, lane);
            stage64<128>(Bb + (size_t)n0 * 1024 + (i + 1) * 64, 1024, sB[(i + 1) & 1], wave, lane);
        }
        const unsigned short* A = sA[i & 1];
        const unsigned short* Bm = sB[i & 1];
#pragma unroll
        for (int ks = 0; ks < 2; ++ks) {
            bf8 af[4], bfv[4];
#pragma unroll
            for (int mi = 0; mi < 4; ++mi) af[mi] = fragld(A, wy + mi * 16 + fr, ks * 4 + fq);
#pragma unroll
            for (int ni = 0; ni < 4; ++ni) bfv[ni] = fragld(Bm, wx + ni * 16 + fr, ks * 4 + fq);
#pragma unroll
            for (int mi = 0; mi < 4; ++mi)
#pragma unroll
                for (int ni = 0; ni < 4; ++ni)
                    acc[mi][ni] = MFMA16(af[mi], bfv[ni], acc[mi][ni]);
        }
        if (i + 1 < 16) { WAITL0; WAITV(0); BARRIER; }
    }
#pragma unroll
    for (int mi = 0; mi < 4; ++mi)
#pragma unroll
        for (int ni = 0; ni < 4; ++ni) {
            const int col = n0 + wx + ni * 16 + fr;
#pragma unroll
            for (int j2 = 0; j2 < 4; ++j2) {
                const int row = m0 + wy + mi * 16 + fq * 4 + j2;
                outp[(size_t)row * 1024 + col] = f2bf(acc[mi][ni][j2]);
            }
        }
}

// ---------------- one-time: wbig segment 9 (gate-2 rows) from wgT ----------------
__global__ __launch_bounds__(256) void k_seg9(const unsigned short* __restrict__ wgT,
                                              unsigned short* __restrict__ wbigX,
                                              unsigned short* __restrict__ wbigH) {
    const int d = blockIdx.x, k4 = threadIdx.x * 4;
    us4 vx = *(const us4*)(wgT + (size_t)(2048 + d) * 2048 + k4);
    us4 vh = *(const us4*)(wgT + (size_t)(2048 + d) * 2048 + 1024 + k4);
    *(us4*)(wbigX + (size_t)(9216 + d) * 1024 + k4) = vx;
    *(us4*)(wbigH + (size_t)(9216 + d) * 1024 + k4) = vh;
}

// ---------------- one-time: cbig[n] = bg[g']@Wqkv + bqkv  (f32) ----------------
__global__ __launch_bounds__(256) void k_cbig(const float* __restrict__ bg,
                                              const float* __restrict__ Wq,
                                              const float* __restrict__ Wk,
                                              const float* __restrict__ Wv,
                                              const float* __restrict__ bq,
                                              const float* __restrict__ bk,
                                              const float* __restrict__ bv,
                                              float* __restrict__ cbig) {
    const int n = blockIdx.x * 256 + threadIdx.x;
    const int j = n >> 10, d = n & 1023;
    float s;
    if (j < 9) {
        const int gp = j / 3, which = j % 3;
        const int selg = (gp == 2) ? 3 : gp;
        const float* W = which == 0 ? Wq : (which == 1 ? Wk : Wv);
        const float* bqkv = which == 0 ? bq : (which == 1 ? bk : bv);
        s = bqkv[gp * 1024 + d];
        const float* wb = W + (size_t)gp * 1024 * 1024;
        const float* bgb = bg + selg * 1024;
        for (int k = 0; k < 1024; ++k) s += bgb[k] * wb[(size_t)k * 1024 + d];
    } else {
        s = bg[2048 + d];
    }
    cbig[n] = s;
}

// ---------------- chunked: XBIG = xbf_chunk @ wbigX^T + cbig ----------------
__global__ __launch_bounds__(256) void k_xbig(const unsigned short* __restrict__ xbf,
                                              const unsigned short* __restrict__ wbigX,
                                              const float* __restrict__ cbig,
                                              unsigned short* __restrict__ XBIG) {
    __shared__ unsigned short sA[2][128 * 64];
    __shared__ unsigned short sB[2][128 * 64];
    const int tid = threadIdx.x, lane = tid & 63, wave = tid >> 6;
    const int n0 = blockIdx.x * 128;
    const size_t m0 = (size_t)blockIdx.y * 128;
    const int wy = (wave >> 1) * 64, wx = (wave & 1) * 64;
    const int fr = lane & 15, fq = lane >> 4;
    f4 acc[4][4] = {};

    stage64<128>(xbf + m0 * 1024, 1024, sA[0], wave, lane);
    stage64<128>(wbigX + (size_t)n0 * 1024, 1024, sB[0], wave, lane);
    WAITV(0); BARRIER;
#pragma unroll
    for (int i = 0; i < 16; ++i) {
        if (i + 1 < 16) {
            stage64<128>(xbf + m0 * 1024 + (i + 1) * 64, 1024, sA[(i + 1) & 1], wave, lane);
            stage64<128>(wbigX + (size_t)n0 * 1024 + (i + 1) * 64, 1024, sB[(i + 1) & 1], wave, lane);
        }
        const unsigned short* A = sA[i & 1];
        const unsigned short* Bm = sB[i & 1];
#pragma unroll
        for (int ks = 0; ks < 2; ++ks) {
            bf8 af[4], bfv[4];
#pragma unroll
            for (int mi = 0; mi < 4; ++mi) af[mi] = fragld(A, wy + mi * 16 + fr, ks * 4 + fq);
#pragma unroll
            for (int ni = 0; ni < 4; ++ni) bfv[ni] = fragld(Bm, wx + ni * 16 + fr, ks * 4 + fq);
#pragma unroll
            for (int mi = 0; mi < 4; ++mi)
#pragma unroll
                for (int ni = 0; ni < 4; ++ni)
                    acc[mi][ni] = MFMA16(af[mi], bfv[ni], acc[mi][ni]);
        }
        if (i + 1 < 16) { WAITL0; WAITV(0); BARRIER; }
    }
#pragma unroll
    for (int mi = 0; mi < 4; ++mi)
#pragma unroll
        for (int ni = 0; ni < 4; ++ni) {
            const int col = n0 + wx + ni * 16 + fr;
            const float b = cbig[col];
#pragma unroll
            for (int j = 0; j < 4; ++j) {
                const size_t row = m0 + wy + mi * 16 + fq * 4 + j;
                XBIG[row * 10240 + col] = f2bf(acc[mi][ni][j] + b);
            }
        }
}

// ---------------- tier0 per-step: qkv+gupd = h @ wbigH + XBIG_t ----------------
// 64x32 tile, 1280 blocks, depth-3 4-slot ring (vmcnt 6/3/0), 3 blocks/CU.
__global__ __launch_bounds__(256, 3) void k_qg(
    const unsigned short* __restrict__ hxbf,
    const unsigned short* __restrict__ wbigH,
    const unsigned short* __restrict__ XBIGt,   // [256][10240]
    unsigned short* __restrict__ qkvbf,
    float* __restrict__ gupd) {
    __shared__ unsigned short sA[4][32 * 64];
    __shared__ unsigned short sB[4][64 * 64];
    const int tid = threadIdx.x, lane = tid & 63, wave = tid >> 6;
    const int n0 = blockIdx.x * 64, b0 = blockIdx.y * 32;
    const unsigned short* Aab = hxbf + (size_t)b0 * 1024;
    const unsigned short* Bb = wbigH + (size_t)n0 * 1024;
    const int wr = (wave & 1) * 16, wc = (wave >> 1) * 32;
    const int fr = lane & 15, fq = lane >> 4;
    f4 acc[2] = {};

#pragma unroll
    for (int p = 0; p < 3; ++p) {
        stage64<32>(Aab + p * 64, 1024, sA[p], wave, lane);
        stage64<64>(Bb + p * 64, 1024, sB[p], wave, lane);
    }
    WAITV(6); BARRIER;
#pragma unroll
    for (int i = 0; i < 16; ++i) {
        if (i + 3 < 16) {
            stage64<32>(Aab + (i + 3) * 64, 1024, sA[(i + 3) & 3], wave, lane);
            stage64<64>(Bb + (i + 3) * 64, 1024, sB[(i + 3) & 3], wave, lane);
        }
        const unsigned short* A = sA[i & 3];
        const unsigned short* Bm = sB[i & 3];
#pragma unroll
        for (int ks = 0; ks < 2; ++ks) {
            bf8 a0 = fragld(A, wr + fr, ks * 4 + fq);
            bf8 b0v = fragld(Bm, wc + fr, ks * 4 + fq);
            bf8 b1v = fragld(Bm, wc + 16 + fr, ks * 4 + fq);
            acc[0] = MFMA16(a0, b0v, acc[0]);
            acc[1] = MFMA16(a0, b1v, acc[1]);
        }
        if (i < 15) {
            WAITL0;
            if (i + 3 < 16) { WAITV(6); }
            else if (i + 2 < 16) { WAITV(3); }
            else { WAITV(0); }
            BARRIER;
        }
    }
#pragma unroll
    for (int ni = 0; ni < 2; ++ni) {
        const int col = n0 + wc + ni * 16 + fr;
        const int seg = col >> 10, d = col & 1023;
#pragma unroll
        for (int j = 0; j < 4; ++j) {
            const int row = b0 + wr + fq * 4 + j;
            const float v = acc[ni][j] + bf2f(XBIGt[(size_t)row * 10240 + col]);
            if (seg == 9) {
                gupd[(size_t)row * 1024 + d] = tanhf(v);
            } else {
                const int gp = seg / 3, which = seg % 3;
                qkvbf[((size_t)gp * NB + row) * 3072 + which * 1024 + d] = f2bf(v);
            }
        }
    }
}

// ---------------- fallback per-step S1 (staged, proven) ----------------
__global__ __launch_bounds__(256, 2) void k_pre(
    const unsigned short* __restrict__ hxbf,
    const unsigned short* __restrict__ xt,
    const unsigned short* __restrict__ wgT,
    const float* __restrict__ bg,
    unsigned short* __restrict__ prebf,
    float* __restrict__ gupd) {
    __shared__ unsigned short sA[4][32 * 64];
    __shared__ unsigned short sB[4][64 * 64];
    const int tid = threadIdx.x, lane = tid & 63, wave = tid >> 6;
    const int n0 = blockIdx.x * 64, b0 = blockIdx.y * 32;
    const int wr = (wave & 1) * 16, wc = (wave >> 1) * 32;
    const int fr = lane & 15, fq = lane >> 4;
    constexpr int NT = 32;
    f4 acc[2] = {};

    const unsigned short* hb = hxbf + (size_t)b0 * 1024;
    const unsigned short* xb = xt + (size_t)b0 * 1024;
    auto asrc = [&](int i) -> const unsigned short* {
        return i < 16 ? xb + i * 64 : hb + (i - 16) * 64;
    };
    auto bsrc = [&](int i) -> const unsigned short* {
        return wgT + (size_t)n0 * 2048 + i * 64;
    };

#pragma unroll
    for (int p = 0; p < 3; ++p) {
        stage64<32>(asrc(p), 1024, sA[p], wave, lane);
        stage64<64>(bsrc(p), 2048, sB[p], wave, lane);
    }
    WAITV(6); BARRIER;
#pragma unroll
    for (int i = 0; i < NT; ++i) {
        if (i + 3 < NT) {
            stage64<32>(asrc(i + 3), 1024, sA[(i + 3) & 3], wave, lane);
            stage64<64>(bsrc(i + 3), 2048, sB[(i + 3) & 3], wave, lane);
        }
        const unsigned short* A = sA[i & 3];
        const unsigned short* Bm = sB[i & 3];
#pragma unroll
        for (int ks = 0; ks < 2; ++ks) {
            bf8 a0 = fragld(A, wr + fr, ks * 4 + fq);
            bf8 b0v = fragld(Bm, wc + fr, ks * 4 + fq);
            bf8 b1v = fragld(Bm, wc + 16 + fr, ks * 4 + fq);
            acc[0] = MFMA16(a0, b0v, acc[0]);
            acc[1] = MFMA16(a0, b1v, acc[1]);
        }
        if (i < NT - 1) {
            WAITL0;
            if (i + 3 < NT) { WAITV(6); }
            else if (i + 2 < NT) { WAITV(3); }
            else { WAITV(0); }
            BARRIER;
        }
    }
#pragma unroll
    for (int ni = 0; ni < 2; ++ni) {
        const int col = n0 + wc + ni * 16 + fr;
        const int gg = col >> 10, d = col & 1023;
#pragma unroll
        for (int j = 0; j < 4; ++j) {
            const int row = b0 + wr + fq * 4 + j;
            float v = acc[ni][j] + bg[col];
            if (gg == 2) {
                gupd[(size_t)row * 1024 + d] = tanhf(v);
            } else {
                const int gm = (gg == 3) ? 2 : gg;
                prebf[((size_t)gm * NB + row) * 1024 + d] = f2bf(v);
            }
        }
    }
}

// ---------------- fallback per-step S2 (staged, proven) ----------------
__global__ __launch_bounds__(256, 3) void k_qkv(
    const unsigned short* __restrict__ prebf,
    const unsigned short* __restrict__ wqkvT,
    const float* __restrict__ bq,
    const float* __restrict__ bk,
    const float* __restrict__ bv,
    unsigned short* __restrict__ qkvbf) {
    __shared__ unsigned short sA[4][32 * 64];
    __shared__ unsigned short sB[4][64 * 64];
    const int tid = threadIdx.x, lane = tid & 63, wave = tid >> 6;
    const int g = blockIdx.z;
    const int n0 = blockIdx.x * 64, b0 = blockIdx.y * 32;
    const unsigned short* Aab = prebf + ((size_t)g * NB + b0) * 1024;
    const unsigned short* Bb = wqkvT + ((size_t)g * 3072 + n0) * 1024;
    const int wr = (wave & 1) * 16, wc = (wave >> 1) * 32;
    const int fr = lane & 15, fq = lane >> 4;
    f4 acc[2] = {};

#pragma unroll
    for (int p = 0; p < 3; ++p) {
        stage64<32>(Aab + p * 64, 1024, sA[p], wave, lane);
        stage64<64>(Bb + p * 64, 1024, sB[p], wave, lane);
    }
    WAITV(6); BARRIER;
#pragma unroll
    for (int i = 0; i < 16; ++i) {
        if (i + 3 < 16) {
            stage64<32>(Aab + (i + 3) * 64, 1024, sA[(i + 3) & 3], wave, lane);
            stage64<64>(Bb + (i + 3) * 64, 1024, sB[(i + 3) & 3], wave, lane);
        }
        const unsigned short* A = sA[i & 3];
        const unsigned short* Bm = sB[i & 3];
#pragma unroll
        for (int ks = 0; ks < 2; ++ks) {
            bf8 a0 = fragld(A, wr + fr, ks * 4 + fq);
            bf8 b0v = fragld(Bm, wc + fr, ks * 4 + fq);
            bf8 b1v = fragld(Bm, wc + 16 + fr, ks * 4 + fq);
            acc[0] = MFMA16(a0, b0v, acc[0]);
            acc[1] = MFMA16(a0, b1v, acc[1]);
        }
        if (i < 15) {
            WAITL0;
            if (i + 3 < 16) { WAITV(6); }
            else if (i + 2 < 16) { WAITV(3); }
            else { WAITV(0); }
            BARRIER;
        }
    }
#pragma unroll
    for (int ni = 0; ni < 2; ++ni) {
        const int col = n0 + wc + ni * 16 + fr;
        const int which = col >> 10, d = col & 1023;
        const float* bp = which == 0 ? bq : (which == 1 ? bk : bv);
        const float bias = bp[g * 1024 + d];
#pragma unroll
        for (int j = 0; j < 4; ++j) {
            const int row = b0 + wr + fq * 4 + j;
            qkvbf[((size_t)g * NB + row) * 3072 + col] = f2bf(acc[ni][j] + bias);
        }
    }
}

// ---------------- per-step S3: cross-head attention, one WG per (batch, gate) ----------------
__global__ __launch_bounds__(256) void k_attn(const unsigned short* __restrict__ qkvbf,
                                              unsigned short* __restrict__ aobf) {
    __shared__ unsigned short qs[16][72], ksm[16][72], vsm[16][72];
    __shared__ float aw[16][17];
    const int b = blockIdx.x, g = blockIdx.y, tid = threadIdx.x;
    const unsigned short* src = qkvbf + ((size_t)g * NB + b) * 3072;
#pragma unroll
    for (int j = 0; j < 3; ++j) {
        const int n = (j * 256 + tid) * 4;
        us4 dv = *(const us4*)(src + n);
        const int part = n >> 10, h = (n >> 6) & 15, c = n & 63;
        unsigned short* dst = part == 0 ? &qs[h][c] : (part == 1 ? &ksm[h][c] : &vsm[h][c]);
        *(us4*)dst = dv;
    }
    __syncthreads();
    const int h = tid >> 4, kp = tid & 15;
    float s = 0.f;
#pragma unroll
    for (int dblk = 0; dblk < 8; ++dblk) {
        us8 qv = *(const us8*)&qs[h][dblk * 8];
        us8 kv = *(const us8*)&ksm[kp][dblk * 8];
#pragma unroll
        for (int e = 0; e < 8; ++e) s += bf2f(qv[e]) * bf2f(kv[e]);
    }
    s *= 0.125f;
    float m = s;
#pragma unroll
    for (int off = 8; off; off >>= 1) m = fmaxf(m, __shfl_xor(m, off, 16));
    const float p = __expf(s - m);
    float sum = p;
#pragma unroll
    for (int off = 8; off; off >>= 1) sum += __shfl_xor(sum, off, 16);
    aw[h][kp] = p / sum;
    __syncthreads();
    float a0 = 0.f, a1 = 0.f, a2 = 0.f, a3 = 0.f;
#pragma unroll
    for (int kk = 0; kk < 16; ++kk) {
        const float w = aw[h][kk];
        us4 vv = *(const us4*)&vsm[kk][kp * 4];
        a0 += w * bf2f(vv[0]); a1 += w * bf2f(vv[1]);
        a2 += w * bf2f(vv[2]); a3 += w * bf2f(vv[3]);
    }
    us4 ov;
    ov[0] = f2bf(a0); ov[1] = f2bf(a1); ov[2] = f2bf(a2); ov[3] = f2bf(a3);
    *(us4*)(aobf + ((size_t)g * NB + b) * 1024 + h * 64 + kp * 4) = ov;
}

// ---------------- per-step S4: gates = sigmoid(ao @ Wo + bo); cell update (staged) ----------------
__global__ __launch_bounds__(256, 1) void k_gate(
    const unsigned short* __restrict__ aobf,
    const unsigned short* __restrict__ woT,
    const float* __restrict__ bo,
    const float* __restrict__ gupd,
    unsigned short* __restrict__ hxbf,
    float* __restrict__ out, int t) {
    __shared__ unsigned short sA[4][3][32 * 64];
    __shared__ unsigned short sB[4][3][32 * 64];
    const int tid = threadIdx.x, lane = tid & 63, wave = tid >> 6;
    const int d0 = blockIdx.x * 32, b0 = blockIdx.y * 32;
    const int wr = (wave & 1) * 16, wc = (wave >> 1) * 16;
    const int fr = lane & 15, fq = lane >> 4;
    f4 acc[3] = {};

    auto stage_all = [&](int i, int slot) {
#pragma unroll
        for (int g = 0; g < 3; ++g) {
            stage64<32>(aobf + ((size_t)g * NB + b0) * 1024 + i * 64, 1024,
                        sA[slot][g], wave, lane);
            stage64<32>(woT + ((size_t)g * 1024 + d0) * 1024 + i * 64, 1024,
                        sB[slot][g], wave, lane);
        }
    };

    stage_all(0, 0);
    stage_all(1, 1);
    stage_all(2, 2);
    WAITV(12); BARRIER;
#pragma unroll
    for (int i = 0; i < 16; ++i) {
        if (i + 3 < 16) stage_all(i + 3, (i + 3) & 3);
        const int sl = i & 3;
#pragma unroll
        for (int g = 0; g < 3; ++g) {
#pragma unroll
            for (int ks = 0; ks < 2; ++ks) {
                bf8 a0 = fragld(sA[sl][g], wr + fr, ks * 4 + fq);
                bf8 b0v = fragld(sB[sl][g], wc + fr, ks * 4 + fq);
                acc[g] = MFMA16(a0, b0v, acc[g]);
            }
        }
        if (i < 15) {
            WAITL0;
            if (i + 3 < 16) { WAITV(12); }
            else if (i + 2 < 16) { WAITV(6); }
            else { WAITV(0); }
            BARRIER;
        }
    }

    const int col = d0 + wc + fr;
    const float bof = bo[col], boi = bo[1024 + col], boo = bo[2048 + col];
    float* cxp = out + OUT_CX_OFF;
    float* hxp = out + OUT_HX_OFF;
    float* outs = out + (size_t)t * NB * 1024;
#pragma unroll
    for (int j = 0; j < 4; ++j) {
        const int row = b0 + wr + fq * 4 + j;
        const size_t idx = (size_t)row * 1024 + col;
        const float fg = sigm(acc[0][j] + bof);
        const float ig = sigm(acc[1][j] + boi);
        const float og = sigm(acc[2][j] + boo);
        const float c = fg * cxp[idx] + ig * gupd[idx];
        const float h = og * tanhf(c);
        cxp[idx] = c;
        hxp[idx] = h;
        outs[idx] = h;
        hxbf[idx] = f2bf(h);
    }
}

extern "C" void kernel_launch(void* const* d_in, const int* in_sizes, int n_in,
                              void* d_out, int out_size, void* d_ws, size_t ws_size,
                              hipStream_t stream) {
    const float* inputs = (const float*)d_in[0];
    const float* Wg = (const float*)d_in[1];
    const float* bg = (const float*)d_in[2];
    const float* Wq = (const float*)d_in[3];
    const float* bq = (const float*)d_in[4];
    const float* Wk = (const float*)d_in[5];
    const float* bk = (const float*)d_in[6];
    const float* Wv = (const float*)d_in[7];
    const float* bv = (const float*)d_in[8];
    const float* Wo = (const float*)d_in[9];
    const float* bo = (const float*)d_in[10];
    float* out = (float*)d_out;
    (void)in_sizes; (void)n_in; (void)out_size;

    char* ws = (char*)d_ws;
    size_t off = 0;
    auto alloc = [&](size_t bytes) -> void* {
        void* p = ws + off;
        off += (bytes + 255) & ~(size_t)255;
        return p;
    };
    unsigned short* wgT   = (unsigned short*)alloc((size_t)4096 * 2048 * 2);
    unsigned short* wqkvT = (unsigned short*)alloc((size_t)3 * 3072 * 1024 * 2);
    unsigned short* woT   = (unsigned short*)alloc((size_t)3 * 1024 * 1024 * 2);
    unsigned short* wgnt  = (unsigned short*)alloc((size_t)4 * 2048 * 1024 * 2);
    unsigned short* hxbf  = (unsigned short*)alloc((size_t)256 * 1024 * 2);
    unsigned short* prebf = (unsigned short*)alloc((size_t)3 * 256 * 1024 * 2);
    float*          gupd  = (float*)alloc((size_t)256 * 1024 * 4);
    unsigned short* qkvbf = (unsigned short*)alloc((size_t)3 * 256 * 3072 * 2);
    unsigned short* aobf  = (unsigned short*)alloc((size_t)3 * 256 * 1024 * 2);
    unsigned short* xbfs  = (unsigned short*)alloc((size_t)2 * 256 * 1024 * 2);
    const size_t off_base = off;
    unsigned short* xbf   = (unsigned short*)alloc((size_t)65536 * 1024 * 2);
    const size_t off_xbf = off;
    unsigned short* wbigX = (unsigned short*)alloc((size_t)10240 * 1024 * 2);
    unsigned short* wbigH = (unsigned short*)alloc((size_t)10240 * 1024 * 2);
    float*          cbig  = (float*)alloc((size_t)10240 * 4);
    const size_t off_wb = off;
    unsigned short* XBIGc = (unsigned short*)(ws + off_wb);

    int CH = 0;
    for (int c = 64; c >= 4; c >>= 1) {
        if (ws_size >= off_wb + (size_t)c * 256 * 10240 * 2) { CH = c; break; }
    }
    int tier;
    if (CH > 0) tier = 0;
    else if (ws_size >= off_xbf) tier = 2;
    else if (ws_size >= off_base) tier = 3;
    else return;

    hipMemsetAsync(hxbf, 0, (size_t)256 * 1024 * 2, stream);
    hipMemsetAsync(out + OUT_CX_OFF, 0, (size_t)256 * 1024 * 4, stream);

    // one-time weight convert+transpose (all tiers)
    for (int g = 0; g < 4; ++g)
        k_transpose<<<dim3(32, 64), 256, 0, stream>>>(
            Wg + (size_t)g * 2048 * 1024, wgT + (size_t)g * 1024 * 2048, 2048, 1024);
    const float* wsrc[3] = {Wq, Wk, Wv};
    for (int g = 0; g < 3; ++g)
        for (int wi = 0; wi < 3; ++wi)
            k_transpose<<<dim3(32, 32), 256, 0, stream>>>(
                wsrc[wi] + (size_t)g * 1024 * 1024,
                wqkvT + (size_t)g * 3072 * 1024 + (size_t)wi * 1024 * 1024, 1024, 1024);
    for (int g = 0; g < 3; ++g)
        k_transpose<<<dim3(32, 32), 256, 0, stream>>>(
            Wo + (size_t)g * 1024 * 1024, woT + (size_t)g * 1024 * 1024, 1024, 1024);

    if (tier <= 2) k_x2bf<<<2048, 256, 0, stream>>>(inputs, xbf, 16777216);

    if (tier == 0) {
        k_x2bf<<<2048, 256, 0, stream>>>(Wg, wgnt, 2097152);
        k_wfz<<<dim3(8, 8, 18), 256, 0, stream>>>(wqkvT, wgnt, wbigX, wbigH);
        k_seg9<<<1024, 256, 0, stream>>>(wgT, wbigX, wbigH);
        k_cbig<<<40, 256, 0, stream>>>(bg, Wq, Wk, Wv, bq, bk, bv, cbig);

        for (int c = 0; c < 256 / CH; ++c) {
            k_xbig<<<dim3(80, CH * 2), 256, 0, stream>>>(
                xbf + (size_t)c * CH * 256 * 1024, wbigX, cbig, XBIGc);
            for (int tl = 0; tl < CH; ++tl) {
                const int t = c * CH + tl;
                k_qg<<<dim3(160, 8), 256, 0, stream>>>(
                    hxbf, wbigH, XBIGc + (size_t)tl * 256 * 10240, qkvbf, gupd);
                k_attn<<<dim3(256, 3), 256, 0, stream>>>(qkvbf, aobf);
                k_gate<<<dim3(32, 8), 256, 0, stream>>>(aobf, woT, bo, gupd, hxbf, out, t);
            }
        }
    } else {
        for (int t = 0; t < 256; ++t) {
            if (tier == 3)
                k_x2bf<<<64, 256, 0, stream>>>(inputs + (size_t)t * 262144,
                                               xbfs + (size_t)(t & 1) * 262144, 65536);
            k_pre<<<dim3(64, 8), 256, 0, stream>>>(
                hxbf,
                tier == 2 ? xbf + (size_t)t * 262144 : xbfs + (size_t)(t & 1) * 262144,
                wgT, bg, prebf, gupd);
            k_qkv<<<dim3(48, 8, 3), 256, 0, stream>>>(prebf, wqkvT, bq, bk, bv, qkvbf);
            k_attn<<<dim3(256, 3), 256, 0, stream>>>(qkvbf, aobf);
            k_gate<<<dim3(32, 8), 256, 0, stream>>>(aobf, woT, bo, gupd, hxbf, out, t);
        }
    }
}